// Round 2
// baseline (487.455 us; speedup 1.0000x reference)
//
#include <hip/hip_runtime.h>

// PSP: syn_t = 0.5 * (syn_{t-1} + x_t), tau = 2.0. Shapes (T=64, N=512, C=2048) f32.
// Serial in T, independent per (n,c). One thread owns 4 contiguous channels.
//
// Round-1 lesson: interleaved load/compute/store left ~1 load in flight per wave
// (in-order vmcnt retirement makes loads issued after stores wait on store acks)
// => 1.1 TB/s. Fix: batch 8 timesteps of loads into registers before any
// dependent use, double-buffered so the next batch is in flight during compute.

typedef float f4 __attribute__((ext_vector_type(4)));

#define T_STEPS 64
#define NC4 (512 * 2048 / 4)   // 262144 float4 lanes per timestep
#define BATCH 8                // timesteps per register batch (8 x float4 = 32 VGPR)

__device__ __forceinline__ void load_batch(const f4* __restrict__ ip, int base,
                                           f4 (&x)[BATCH]) {
#pragma unroll
    for (int j = 0; j < BATCH; ++j)
        x[j] = ip[(size_t)(base + j) * (size_t)NC4];
}

__device__ __forceinline__ void compute_store(f4* __restrict__ op, int base,
                                              f4 (&x)[BATCH], f4& acc) {
#pragma unroll
    for (int j = 0; j < BATCH; ++j) {
        acc = 0.5f * (acc + x[j]);
        __builtin_nontemporal_store(acc, &op[(size_t)(base + j) * (size_t)NC4]);
    }
}

__global__ __launch_bounds__(256) void psp_scan_kernel(
    const f4* __restrict__ in, f4* __restrict__ out) {
    const int idx = blockIdx.x * blockDim.x + threadIdx.x;  // [0, NC4)
    const f4* ip = in + idx;
    f4* op = out + idx;

    f4 A[BATCH], B[BATCH];
    f4 acc = {0.f, 0.f, 0.f, 0.f};

    // Software pipeline: batches 0..7 (8 batches x 8 timesteps = 64).
    load_batch(ip, 0 * BATCH, A);
    load_batch(ip, 1 * BATCH, B);

    compute_store(op, 0 * BATCH, A, acc);
    load_batch(ip, 2 * BATCH, A);

    compute_store(op, 1 * BATCH, B, acc);
    load_batch(ip, 3 * BATCH, B);

    compute_store(op, 2 * BATCH, A, acc);
    load_batch(ip, 4 * BATCH, A);

    compute_store(op, 3 * BATCH, B, acc);
    load_batch(ip, 5 * BATCH, B);

    compute_store(op, 4 * BATCH, A, acc);
    load_batch(ip, 6 * BATCH, A);

    compute_store(op, 5 * BATCH, B, acc);
    load_batch(ip, 7 * BATCH, B);

    compute_store(op, 6 * BATCH, A, acc);
    compute_store(op, 7 * BATCH, B, acc);
}

extern "C" void kernel_launch(void* const* d_in, const int* in_sizes, int n_in,
                              void* d_out, int out_size, void* d_ws, size_t ws_size,
                              hipStream_t stream) {
    const f4* in = (const f4*)d_in[0];
    f4* out = (f4*)d_out;
    // 262144 float4 lanes -> 1024 blocks of 256 (exact fit, no bounds check)
    psp_scan_kernel<<<NC4 / 256, 256, 0, stream>>>(in, out);
}

// Round 5
// 435.710 us; speedup vs baseline: 1.1188x; 1.1188x over previous
//
#include <hip/hip_runtime.h>

// PSP: syn_t = 0.5*(syn_{t-1} + x_t), tau=2. Shapes (T=64, N=512, C=2048) f32.
// Linear scan => chunked-scan decomposition: 4 chunks of 16 timesteps.
// Each wave owns one chunk x 64 float4-columns:
//   1) 16 INDEPENDENT loads into registers (max MLP, no stores interleaved)
//   2) local scan in registers
//   3) LDS exchange of chunk-final states; carry_in = sum F_d * 2^{-16*gap} (exact)
//   4) out_j = local_j + carry * 0.5^{j+1}; 16 clean stores
// Round-2 lesson: hand double-buffering was collapsed by the compiler (VGPR=36)
// and regressed; restructuring the dependences is the real lever.

typedef float f4 __attribute__((ext_vector_type(4)));

#define NC4 (512 * 2048 / 4)   // 262144 float4 columns per timestep
#define CHUNK 16
#define NCHUNK 4               // T / CHUNK = 64/16
#define COLS 64                // float4-columns per block (one wave per chunk)

__global__ __launch_bounds__(256) void psp_scan_kernel(
    const f4* __restrict__ in, f4* __restrict__ out) {
    const int col   = threadIdx.x & (COLS - 1);
    const int chunk = threadIdx.x >> 6;              // wave id == chunk id
    const int colIdx = blockIdx.x * COLS + col;      // [0, NC4)

    const f4* ip = in  + (size_t)(chunk * CHUNK) * NC4 + colIdx;
    f4*       op = out + (size_t)(chunk * CHUNK) * NC4 + colIdx;

    // 1) 16 independent loads — all in flight at once
    f4 v[CHUNK];
#pragma unroll
    for (int j = 0; j < CHUNK; ++j)
        v[j] = ip[(size_t)j * NC4];

    // 2) local scan (chain of 16 FMAs, in registers)
    f4 acc = {0.f, 0.f, 0.f, 0.f};
#pragma unroll
    for (int j = 0; j < CHUNK; ++j) {
        acc = 0.5f * (acc + v[j]);
        v[j] = acc;
    }

    // 3) exchange chunk-final states (4 KB LDS)
    __shared__ f4 finals[NCHUNK][COLS];
    finals[chunk][col] = acc;
    __syncthreads();

    f4 carry = {0.f, 0.f, 0.f, 0.f};
    if (chunk >= 1) carry = finals[chunk - 1][col];
    if (chunk >= 2) carry += finals[chunk - 2][col] * 0x1p-16f;
    if (chunk >= 3) carry += finals[chunk - 3][col] * 0x1p-32f;

    // 4) fixup + store: global_j = local_j + carry * 0.5^{j+1}
    float d = 0.5f;
#pragma unroll
    for (int j = 0; j < CHUNK; ++j) {
        op[(size_t)j * NC4] = v[j] + carry * d;
        d *= 0.5f;
    }
}

extern "C" void kernel_launch(void* const* d_in, const int* in_sizes, int n_in,
                              void* d_out, int out_size, void* d_ws, size_t ws_size,
                              hipStream_t stream) {
    const f4* in = (const f4*)d_in[0];
    f4* out = (f4*)d_out;
    // 262144 columns / 64 per block = 4096 blocks of 256 threads (exact fit)
    psp_scan_kernel<<<NC4 / COLS, 256, 0, stream>>>(in, out);
}